// Round 8
// baseline (1491.378 us; speedup 1.0000x reference)
//
#include <hip/hip_runtime.h>
#include <hip/hip_bf16.h>
#include <cmath>

#define NLVL 4

struct FusedArgs {
    const float* feat[NLVL];
    const float* boxes[NLVL];
    float* out[NLVL];
    int size[NLVL];      // H == W per level
    int nbatch[NLVL];
    float scale[NLVL];
    int blk_base[NLVL + 1];   // cumulative K*49 (blocks per level)
};

// One block = one (level, box) slice of 256 output elements.
// 49 blocks cover one box's 256ch x 7x7 patch (12544 = 49*256 elements).
// Threads 0..55 build the per-box bilinear table in LDS:
//   tab[0..27]  = y-samples: {lo*W, hi*W, w_lo*valid, w_hi*valid}
//   tab[28..55] = x-samples: {lo,   hi,   w_lo*valid, w_hi*valid}
__global__ __launch_bounds__(256) void roi_fused(FusedArgs a) {
    __shared__ float4 tab[56];
    __shared__ int s_bidx;

    int b = blockIdx.x;
    int lvl = (b >= a.blk_base[1]) + (b >= a.blk_base[2]) + (b >= a.blk_base[3]);

    const float* feat; const float* boxes;
    float* outp; int sz; int nb; float scale;
    if (lvl == 0)      { feat=a.feat[0]; boxes=a.boxes[0]; outp=a.out[0]; sz=a.size[0]; nb=a.nbatch[0]; scale=a.scale[0]; }
    else if (lvl == 1) { feat=a.feat[1]; boxes=a.boxes[1]; outp=a.out[1]; sz=a.size[1]; nb=a.nbatch[1]; scale=a.scale[1]; }
    else if (lvl == 2) { feat=a.feat[2]; boxes=a.boxes[2]; outp=a.out[2]; sz=a.size[2]; nb=a.nbatch[2]; scale=a.scale[2]; }
    else               { feat=a.feat[3]; boxes=a.boxes[3]; outp=a.out[3]; sz=a.size[3]; nb=a.nbatch[3]; scale=a.scale[3]; }

    int rel = b - a.blk_base[lvl];
    int k = rel / 49;            // one box per block (exact: 12544/256 == 49)
    int tid = threadIdx.x;

    if (tid < 56) {
        int axis = (tid >= 28) ? 1 : 0;   // 0 = y, 1 = x
        int s = axis ? (tid - 28) : tid;
        float c1 = boxes[k * 5 + (axis ? 1 : 2)];
        float c2 = boxes[k * 5 + (axis ? 3 : 4)];
        float start = c1 * scale;
        float end   = c2 * scale;
        float bin = fmaxf(end - start, 1.0f) / 7.0f;
        // reference assoc: (start + bin_idx*bin) + ((j+0.5)*bin)/4
        float coord = (start + (float)(s >> 2) * bin) + (((float)(s & 3) + 0.5f) * bin) * 0.25f;

        bool valid = (coord > -1.0f) && (coord < (float)sz);
        float cc = fminf(fmaxf(coord, 0.0f), (float)(sz - 1));  // NaN-safe -> 0
        int lo = (int)floorf(cc);
        int hi = min(lo + 1, sz - 1);
        float fr = cc - (float)lo;
        float v = valid ? 1.0f : 0.0f;
        int mul = axis ? 1 : sz;

        float4 ent;
        ent.x = __int_as_float(lo * mul);
        ent.y = __int_as_float(hi * mul);
        ent.z = (1.0f - fr) * v;
        ent.w = fr * v;
        tab[tid] = ent;
    }
    if (tid == 0) {
        int bi = (int)boxes[k * 5];
        s_bidx = min(max(bi, 0), nb - 1);    // clamp: garbage can't fault
    }
    __syncthreads();

    int idx = rel * 256 + tid;
    int pw = idx % 7;
    int t = idx / 7;
    int ph = t % 7;
    int c = (t / 7) & 255;

    size_t plane = (size_t)sz * (size_t)sz;
    const float* fb = feat + (size_t)(s_bidx * 256 + c) * plane;

    const float4* yt = &tab[ph * 4];
    const float4* xt = &tab[28 + pw * 4];
    float4 xe0 = xt[0], xe1 = xt[1], xe2 = xt[2], xe3 = xt[3];

    float acc = 0.0f;
#pragma unroll
    for (int iy = 0; iy < 4; ++iy) {
        float4 ye = yt[iy];
        int r0 = __float_as_int(ye.x);
        int r1 = __float_as_int(ye.y);
        const float* p0 = fb + r0;
        const float* p1 = fb + r1;

#pragma unroll
        for (int ix = 0; ix < 4; ++ix) {
            float4 xv = (ix == 0) ? xe0 : (ix == 1) ? xe1 : (ix == 2) ? xe2 : xe3;
            int c0 = __float_as_int(xv.x);
            int c1i = __float_as_int(xv.y);
            float v00 = p0[c0];
            float v01 = p0[c1i];
            float v10 = p1[c0];
            float v11 = p1[c1i];
            float t0 = v00 * xv.z + v01 * xv.w;
            float t1 = v10 * xv.z + v11 * xv.w;
            acc += t0 * ye.z;
            acc += t1 * ye.w;
        }
    }
    outp[idx] = acc * 0.0625f;
}

extern "C" void kernel_launch(void* const* d_in, const int* in_sizes, int n_in,
                              void* d_out, int out_size, void* d_ws, size_t ws_size,
                              hipStream_t stream) {
    (void)d_ws; (void)ws_size; (void)n_in; (void)out_size;
    FusedArgs fa;
    int blk_cum = 0;
    size_t out_off = 0;

    for (int l = 0; l < NLVL; ++l) {
        int K = in_sizes[4 + l] / 5;
        long plane = (long)(in_sizes[l] / 512);          // 2 batches * 256 ch
        int H = (int)(sqrt((double)plane) + 0.5);

        fa.feat[l]  = (const float*)d_in[l];
        fa.boxes[l] = (const float*)d_in[4 + l];
        fa.out[l]   = (float*)d_out + out_off;
        fa.size[l]  = H;
        fa.nbatch[l] = (int)(in_sizes[l] / (256L * plane));
        fa.scale[l] = (float)H / 800.0f;
        fa.blk_base[l] = blk_cum;
        blk_cum += K * 49;
        out_off += (size_t)K * 256 * 49;
    }
    fa.blk_base[NLVL] = blk_cum;

    roi_fused<<<blk_cum, 256, 0, stream>>>(fa);
}

// Round 9
// 803.950 us; speedup vs baseline: 1.8551x; 1.8551x over previous
//
#include <hip/hip_runtime.h>
#include <cmath>

#define NLVL 4

// ---------------- fallback kernel (proven in round 8) ----------------
struct FusedArgs {
    const float* feat[NLVL];
    const float* boxes[NLVL];
    float* out[NLVL];
    int size[NLVL];
    int nbatch[NLVL];
    float scale[NLVL];
    int blk_base[NLVL + 1];   // cumulative K*49
};

__global__ __launch_bounds__(256) void roi_fused(FusedArgs a) {
    __shared__ float4 tab[56];
    __shared__ int s_bidx;

    int b = blockIdx.x;
    int lvl = (b >= a.blk_base[1]) + (b >= a.blk_base[2]) + (b >= a.blk_base[3]);

    const float* feat; const float* boxes;
    float* outp; int sz; int nb; float scale;
    if (lvl == 0)      { feat=a.feat[0]; boxes=a.boxes[0]; outp=a.out[0]; sz=a.size[0]; nb=a.nbatch[0]; scale=a.scale[0]; }
    else if (lvl == 1) { feat=a.feat[1]; boxes=a.boxes[1]; outp=a.out[1]; sz=a.size[1]; nb=a.nbatch[1]; scale=a.scale[1]; }
    else if (lvl == 2) { feat=a.feat[2]; boxes=a.boxes[2]; outp=a.out[2]; sz=a.size[2]; nb=a.nbatch[2]; scale=a.scale[2]; }
    else               { feat=a.feat[3]; boxes=a.boxes[3]; outp=a.out[3]; sz=a.size[3]; nb=a.nbatch[3]; scale=a.scale[3]; }

    int rel = b - a.blk_base[lvl];
    int k = rel / 49;
    int tid = threadIdx.x;

    if (tid < 56) {
        int axis = (tid >= 28) ? 1 : 0;
        int s = axis ? (tid - 28) : tid;
        float c1 = boxes[k * 5 + (axis ? 1 : 2)];
        float c2 = boxes[k * 5 + (axis ? 3 : 4)];
        float start = c1 * scale;
        float end   = c2 * scale;
        float bin = fmaxf(end - start, 1.0f) / 7.0f;
        float coord = (start + (float)(s >> 2) * bin) + (((float)(s & 3) + 0.5f) * bin) * 0.25f;
        bool valid = (coord > -1.0f) && (coord < (float)sz);
        float cc = fminf(fmaxf(coord, 0.0f), (float)(sz - 1));
        int lo = (int)floorf(cc);
        int hi = min(lo + 1, sz - 1);
        float fr = cc - (float)lo;
        float v = valid ? 1.0f : 0.0f;
        int mul = axis ? 1 : sz;
        float4 ent;
        ent.x = __int_as_float(lo * mul);
        ent.y = __int_as_float(hi * mul);
        ent.z = (1.0f - fr) * v;
        ent.w = fr * v;
        tab[tid] = ent;
    }
    if (tid == 0) {
        int bi = (int)boxes[k * 5];
        s_bidx = min(max(bi, 0), nb - 1);
    }
    __syncthreads();

    int idx = rel * 256 + tid;
    int pw = idx % 7;
    int t = idx / 7;
    int ph = t % 7;
    int c = (t / 7) & 255;

    size_t plane = (size_t)sz * (size_t)sz;
    const float* fb = feat + (size_t)(s_bidx * 256 + c) * plane;
    const float4* yt = &tab[ph * 4];
    const float4* xt = &tab[28 + pw * 4];
    float4 xe0 = xt[0], xe1 = xt[1], xe2 = xt[2], xe3 = xt[3];

    float acc = 0.0f;
#pragma unroll
    for (int iy = 0; iy < 4; ++iy) {
        float4 ye = yt[iy];
        int r0 = __float_as_int(ye.x);
        int r1 = __float_as_int(ye.y);
        const float* p0 = fb + r0;
        const float* p1 = fb + r1;
#pragma unroll
        for (int ix = 0; ix < 4; ++ix) {
            float4 xv = (ix == 0) ? xe0 : (ix == 1) ? xe1 : (ix == 2) ? xe2 : xe3;
            int c0 = __float_as_int(xv.x);
            int c1i = __float_as_int(xv.y);
            float t0 = p0[c0] * xv.z + p0[c1i] * xv.w;
            float t1 = p1[c0] * xv.z + p1[c1i] * xv.w;
            acc += t0 * ye.z;
            acc += t1 * ye.w;
        }
    }
    outp[idx] = acc * 0.0625f;
}

// ---------------- NCHW -> NHWC transpose ----------------
struct TransArgs {
    const float* feat[NLVL];
    float* featT[NLVL];
    int HW[NLVL];
    int nt[NLVL];            // ceil(HW/64)
    int blk_base[NLVL + 1];  // cumulative B*4*nt
};

__global__ __launch_bounds__(256) void nchw_to_nhwc(TransArgs a) {
    __shared__ float t[64][65];
    int b = blockIdx.x;
    int lvl = (b >= a.blk_base[1]) + (b >= a.blk_base[2]) + (b >= a.blk_base[3]);
    const float* src; float* dst; int HW; int nt;
    if (lvl == 0)      { src=a.feat[0]; dst=a.featT[0]; HW=a.HW[0]; nt=a.nt[0]; }
    else if (lvl == 1) { src=a.feat[1]; dst=a.featT[1]; HW=a.HW[1]; nt=a.nt[1]; }
    else if (lvl == 2) { src=a.feat[2]; dst=a.featT[2]; HW=a.HW[2]; nt=a.nt[2]; }
    else               { src=a.feat[3]; dst=a.featT[3]; HW=a.HW[3]; nt=a.nt[3]; }

    int rel = b - a.blk_base[lvl];
    int per_img = 4 * nt;
    int bimg = rel / per_img;
    int r2 = rel % per_img;
    int c0 = (r2 / nt) * 64;
    int hw0 = (r2 % nt) * 64;

    int tid = threadIdx.x;
    int lx = tid & 63;
    int q  = tid >> 6;

    const float* s = src + ((size_t)bimg * 256 + c0) * (size_t)HW;
    bool okr = (hw0 + lx) < HW;
#pragma unroll
    for (int j = 0; j < 16; ++j) {
        int cl = q * 16 + j;
        t[cl][lx] = okr ? s[(size_t)cl * HW + hw0 + lx] : 0.0f;
    }
    __syncthreads();
    float* d = dst + ((size_t)bimg * HW + hw0) * 256 + c0;
#pragma unroll
    for (int j = 0; j < 16; ++j) {
        int hl = q * 16 + j;
        if (hw0 + hl < HW) d[(size_t)hl * 256 + lx] = t[lx][hl];
    }
}

// ---------------- NHWC main kernel ----------------
struct MainArgs2 {
    const float* featT[NLVL];
    const float* boxes[NLVL];
    float* out[NLVL];
    int size[NLVL];
    int nbatch[NLVL];
    float scale[NLVL];
    int blk_base[NLVL + 1];  // cumulative K (one block per box)
};

__global__ __launch_bounds__(256) void roi_nhwc(MainArgs2 a) {
    __shared__ float4 tab[56];
    __shared__ int s_bidx;

    int b = blockIdx.x;
    int lvl = (b >= a.blk_base[1]) + (b >= a.blk_base[2]) + (b >= a.blk_base[3]);

    const float* featT; const float* boxes;
    float* outp; int sz; int nb; float scale;
    if (lvl == 0)      { featT=a.featT[0]; boxes=a.boxes[0]; outp=a.out[0]; sz=a.size[0]; nb=a.nbatch[0]; scale=a.scale[0]; }
    else if (lvl == 1) { featT=a.featT[1]; boxes=a.boxes[1]; outp=a.out[1]; sz=a.size[1]; nb=a.nbatch[1]; scale=a.scale[1]; }
    else if (lvl == 2) { featT=a.featT[2]; boxes=a.boxes[2]; outp=a.out[2]; sz=a.size[2]; nb=a.nbatch[2]; scale=a.scale[2]; }
    else               { featT=a.featT[3]; boxes=a.boxes[3]; outp=a.out[3]; sz=a.size[3]; nb=a.nbatch[3]; scale=a.scale[3]; }

    int k = b - a.blk_base[lvl];
    int tid = threadIdx.x;

    if (tid < 56) {
        int axis = (tid >= 28) ? 1 : 0;
        int s = axis ? (tid - 28) : tid;
        float c1 = boxes[k * 5 + (axis ? 1 : 2)];
        float c2 = boxes[k * 5 + (axis ? 3 : 4)];
        float start = c1 * scale;
        float end   = c2 * scale;
        float bin = fmaxf(end - start, 1.0f) / 7.0f;
        float coord = (start + (float)(s >> 2) * bin) + (((float)(s & 3) + 0.5f) * bin) * 0.25f;
        bool valid = (coord > -1.0f) && (coord < (float)sz);
        float cc = fminf(fmaxf(coord, 0.0f), (float)(sz - 1));
        int lo = (int)floorf(cc);
        int hi = min(lo + 1, sz - 1);
        float fr = cc - (float)lo;
        float v = valid ? 1.0f : 0.0f;
        int mul = axis ? 1 : sz;   // y entries hold row*W (cell units)
        float4 ent;
        ent.x = __int_as_float(lo * mul);
        ent.y = __int_as_float(hi * mul);
        ent.z = (1.0f - fr) * v;
        ent.w = fr * v;
        tab[tid] = ent;
    }
    if (tid == 0) {
        int bi = (int)boxes[k * 5];
        s_bidx = min(max(bi, 0), nb - 1);
    }
    __syncthreads();

    int wid = tid >> 6;
    int lane = tid & 63;
    size_t plane = (size_t)sz * (size_t)sz;
    // lane covers channels 4*lane .. 4*lane+3 (float4, 16B-aligned; cell stride 1KB)
    const float* fb = featT + (size_t)s_bidx * plane * 256 + (lane << 2);
    float* ob = outp + (size_t)k * 12544;

    for (int bin = wid; bin < 49; bin += 4) {
        int ph = bin / 7;
        int pw = bin - ph * 7;
        const float4* yt = &tab[ph * 4];
        const float4* xt = &tab[28 + pw * 4];

        float4 acc; acc.x = 0.f; acc.y = 0.f; acc.z = 0.f; acc.w = 0.f;
#pragma unroll
        for (int iy = 0; iy < 4; ++iy) {
            float4 ye = yt[iy];
            int r0 = __float_as_int(ye.x);
            int r1 = __float_as_int(ye.y);
#pragma unroll
            for (int ix = 0; ix < 4; ++ix) {
                float4 xe = xt[ix];
                int c0 = __float_as_int(xe.x);
                int c1 = __float_as_int(xe.y);
                float w00 = ye.z * xe.z;
                float w01 = ye.z * xe.w;
                float w10 = ye.w * xe.z;
                float w11 = ye.w * xe.w;
                const float4 v00 = *(const float4*)(fb + (size_t)(r0 + c0) * 256);
                const float4 v01 = *(const float4*)(fb + (size_t)(r0 + c1) * 256);
                const float4 v10 = *(const float4*)(fb + (size_t)(r1 + c0) * 256);
                const float4 v11 = *(const float4*)(fb + (size_t)(r1 + c1) * 256);
                acc.x = fmaf(v00.x, w00, acc.x); acc.y = fmaf(v00.y, w00, acc.y);
                acc.z = fmaf(v00.z, w00, acc.z); acc.w = fmaf(v00.w, w00, acc.w);
                acc.x = fmaf(v01.x, w01, acc.x); acc.y = fmaf(v01.y, w01, acc.y);
                acc.z = fmaf(v01.z, w01, acc.z); acc.w = fmaf(v01.w, w01, acc.w);
                acc.x = fmaf(v10.x, w10, acc.x); acc.y = fmaf(v10.y, w10, acc.y);
                acc.z = fmaf(v10.z, w10, acc.z); acc.w = fmaf(v10.w, w10, acc.w);
                acc.x = fmaf(v11.x, w11, acc.x); acc.y = fmaf(v11.y, w11, acc.y);
                acc.z = fmaf(v11.z, w11, acc.z); acc.w = fmaf(v11.w, w11, acc.w);
            }
        }
        // out[k][c][ph][pw], c = 4*lane + j
        float* o0 = ob + (size_t)(lane << 2) * 49 + bin;
        o0[0]   = acc.x * 0.0625f;
        o0[49]  = acc.y * 0.0625f;
        o0[98]  = acc.z * 0.0625f;
        o0[147] = acc.w * 0.0625f;
    }
}

extern "C" void kernel_launch(void* const* d_in, const int* in_sizes, int n_in,
                              void* d_out, int out_size, void* d_ws, size_t ws_size,
                              hipStream_t stream) {
    (void)n_in; (void)out_size;
    int K[NLVL], H[NLVL], HW[NLVL];
    size_t need = 0;
    for (int l = 0; l < NLVL; ++l) {
        K[l] = in_sizes[4 + l] / 5;
        long plane = (long)(in_sizes[l] / 512);
        H[l] = (int)(sqrt((double)plane) + 0.5);
        HW[l] = H[l] * H[l];
        need += (size_t)in_sizes[l] * sizeof(float);
    }

    if (ws_size >= need) {
        // fast path: transpose to NHWC in d_ws, then coalesced-channel kernel
        TransArgs ta;
        MainArgs2 ma;
        char* ws = (char*)d_ws;
        size_t off = 0;
        int tb = 0, mb = 0;
        size_t out_off = 0;
        for (int l = 0; l < NLVL; ++l) {
            int B = (int)(in_sizes[l] / (256L * HW[l]));
            ta.feat[l]  = (const float*)d_in[l];
            ta.featT[l] = (float*)(ws + off);
            off += (size_t)in_sizes[l] * sizeof(float);
            ta.HW[l] = HW[l];
            ta.nt[l] = (HW[l] + 63) / 64;
            ta.blk_base[l] = tb;
            tb += B * 4 * ta.nt[l];

            ma.featT[l] = ta.featT[l];
            ma.boxes[l] = (const float*)d_in[4 + l];
            ma.out[l]   = (float*)d_out + out_off;
            ma.size[l]  = H[l];
            ma.nbatch[l] = B;
            ma.scale[l] = (float)H[l] / 800.0f;
            ma.blk_base[l] = mb;
            mb += K[l];
            out_off += (size_t)K[l] * 256 * 49;
        }
        ta.blk_base[NLVL] = tb;
        ma.blk_base[NLVL] = mb;

        nchw_to_nhwc<<<tb, 256, 0, stream>>>(ta);
        roi_nhwc<<<mb, 256, 0, stream>>>(ma);
    } else {
        // fallback: proven round-8 kernel, no workspace
        FusedArgs fa;
        int blk_cum = 0;
        size_t out_off = 0;
        for (int l = 0; l < NLVL; ++l) {
            fa.feat[l]  = (const float*)d_in[l];
            fa.boxes[l] = (const float*)d_in[4 + l];
            fa.out[l]   = (float*)d_out + out_off;
            fa.size[l]  = H[l];
            fa.nbatch[l] = (int)(in_sizes[l] / (256L * HW[l]));
            fa.scale[l] = (float)H[l] / 800.0f;
            fa.blk_base[l] = blk_cum;
            blk_cum += K[l] * 49;
            out_off += (size_t)K[l] * 256 * 49;
        }
        fa.blk_base[NLVL] = blk_cum;
        roi_fused<<<blk_cum, 256, 0, stream>>>(fa);
    }
}